// Round 3
// baseline (937.605 us; speedup 1.0000x reference)
//
#include <hip/hip_runtime.h>
#include <hip/hip_fp16.h>
#include <stdint.h>

#define B_SZ 32
#define S_SZ 2048
#define H_SZ 1024
#define M_SZ (B_SZ * S_SZ)

typedef _Float16 half8 __attribute__((ext_vector_type(8)));
typedef float floatx4 __attribute__((ext_vector_type(4)));

struct h4 { _Float16 x, y, z, w; };

// ================= prep: enc->fp16, Wk->fp16, q = hidden@Wq^T, zero counters =================
// blocks [0,8192): enc convert (16,777,216 float4s, 8 per thread)
// blocks [8192,8320): Wk convert (262,144 float4s, 8 per thread) + cnt zeroing
// blocks [8320,16512): query, one wave per output element
__global__ __launch_bounds__(256) void prep_kernel(
    const float* __restrict__ enc, h4* __restrict__ A16,
    const float* __restrict__ Wk, h4* __restrict__ B16,
    const float* __restrict__ hidden, const float* __restrict__ Wq,
    float* __restrict__ q, unsigned* __restrict__ cnt)
{
  const int blk = blockIdx.x;
  const int tid = threadIdx.x;
  if (blk < 8192) {
    int i = blk * 256 + tid;
    const float4* in4 = (const float4*)enc;
    #pragma unroll
    for (int r = 0; r < 8; ++r) {
      float4 f = in4[i];
      h4 o;
      o.x = (_Float16)f.x; o.y = (_Float16)f.y;
      o.z = (_Float16)f.z; o.w = (_Float16)f.w;
      A16[i] = o;
      i += 8192 * 256;
    }
  } else if (blk < 8320) {
    if (blk == 8192 && tid < B_SZ) cnt[tid] = 0u;
    int i = (blk - 8192) * 256 + tid;
    const float4* in4 = (const float4*)Wk;
    #pragma unroll
    for (int r = 0; r < 8; ++r) {
      float4 f = in4[i];
      h4 o;
      o.x = (_Float16)f.x; o.y = (_Float16)f.y;
      o.z = (_Float16)f.z; o.w = (_Float16)f.w;
      B16[i] = o;
      i += 128 * 256;
    }
  } else {
    const int W = (blk - 8320) * 4 + (tid >> 6);   // 32768 waves
    const int lane = tid & 63;
    const int b = W >> 10;
    const int n = W & 1023;
    const float4* hp = (const float4*)(hidden + (size_t)b * H_SZ);
    const float4* wp = (const float4*)(Wq + (size_t)n * H_SZ);
    float acc = 0.f;
    #pragma unroll
    for (int i = 0; i < 4; ++i) {
      float4 h = hp[lane + 64 * i];
      float4 w = wp[lane + 64 * i];
      acc = fmaf(h.x, w.x, acc);
      acc = fmaf(h.y, w.y, acc);
      acc = fmaf(h.z, w.z, acc);
      acc = fmaf(h.w, w.w, acc);
    }
    #pragma unroll
    for (int off = 32; off; off >>= 1) acc += __shfl_xor(acc, off);
    if (lane == 0) q[(size_t)b * H_SZ + n] = acc;
  }
}

// ---------------- async global->LDS, 16B/lane ----------------
__device__ __forceinline__ void gl_lds16(const void* g, void* l) {
  __builtin_amdgcn_global_load_lds(
      (const __attribute__((address_space(1))) void*)g,
      (__attribute__((address_space(3))) void*)l,
      16, 0, 0);
}

__device__ __forceinline__ float fast_tanh(float x) {
  float ax = fabsf(x);
  float e = __expf(ax * -2.0f);
  float t = (1.0f - e) / (1.0f + e);
  return copysignf(t, x);
}

// ================= fused keys-GEMM + tanh + v-dot + last-block softmax =================
// fp16 A (pre-converted, LLC-resident) and fp16 B. BK=64: 16 K-iterations.
// LDS is fragment-major: issue/frag j = grp*8 + sub*2 + ks -> byte j*1024 + lane*16.
// Conflict-free ds_read_b128 (R2-verified), identical global coalescing (16x64B rows).
#define TILE 128
#define BK 64

__global__ __launch_bounds__(256) void fused_keys_kernel(
    const _Float16* __restrict__ A,    // M_SZ x H_SZ fp16
    const _Float16* __restrict__ Bt,   // H_SZ x H_SZ fp16
    const float* __restrict__ q,       // B_SZ x H_SZ
    const float* __restrict__ v,       // H_SZ
    const int* __restrict__ lengths,   // B_SZ
    float* __restrict__ partial,       // 8 x M_SZ
    unsigned* __restrict__ cnt,        // B_SZ (zeroed by prep)
    float* __restrict__ out)           // B_SZ x S_SZ
{
  __shared__ _Float16 As[TILE * BK];   // 16 KB
  __shared__ _Float16 Bs[TILE * BK];   // 16 KB
  __shared__ float rowsum[TILE];
  __shared__ float q_l[TILE];
  __shared__ float v_l[TILE];
  __shared__ float red[8];
  __shared__ unsigned last_s;

  const int tid  = threadIdx.x;
  const int w    = tid >> 6;
  const int lane = tid & 63;

  // XCD swizzle: 8 blocks sharing an A M-tile are congruent mod 8 -> same XCD L2.
  const int bm = ((blockIdx.x >> 6) << 3) | (blockIdx.x & 7);
  const int bn = (blockIdx.x >> 3) & 7;
  const int R0 = bm * TILE;
  const int C0 = bn * TILE;
  const int bidx = R0 >> 11;

  if (tid < TILE) {
    q_l[tid] = q[(size_t)bidx * H_SZ + C0 + tid];
    v_l[tid] = v[C0 + tid];
    rowsum[tid] = 0.f;
  }

  const int wm = w >> 1, wn = w & 1;
  const int cL = lane & 15, quad = lane >> 4;

  floatx4 acc[4][4];
  #pragma unroll
  for (int m = 0; m < 4; ++m)
    #pragma unroll
    for (int n = 0; n < 4; ++n)
      acc[m][n] = (floatx4){0.f, 0.f, 0.f, 0.f};

  // staging sources: issue j = w*4+i (0..15): grp=j>>3, sub=(j>>1)&3, ks=j&1
  // lane source row = grp*64 + sub*16 + cL, k = ks*32 + quad*8  (16 rows x 64B)
  const _Float16* pA[4];
  const _Float16* pB[4];
  #pragma unroll
  for (int i = 0; i < 4; ++i) {
    const int j = w * 4 + i;
    const int row = ((j >> 3) * 64) + (((j >> 1) & 3) * 16) + cL;
    const int k   = (j & 1) * 32 + quad * 8;
    pA[i] = A  + (size_t)(R0 + row) * H_SZ + k;
    pB[i] = Bt + (size_t)(C0 + row) * H_SZ + k;
  }

  for (int kt = 0; kt < H_SZ / BK; ++kt) {
    __syncthreads();
    #pragma unroll
    for (int i = 0; i < 4; ++i) {
      const int j = w * 4 + i;
      gl_lds16(pA[i], (char*)As + j * 1024);
      gl_lds16(pB[i], (char*)Bs + j * 1024);
      pA[i] += BK;
      pB[i] += BK;
    }
    __syncthreads();

    #pragma unroll
    for (int ks = 0; ks < 2; ++ks) {
      half8 af[4], bf[4];
      #pragma unroll
      for (int m = 0; m < 4; ++m)
        af[m] = *(const half8*)((const char*)As + ((wm * 4 + m) * 2 + ks) * 1024 + lane * 16);
      #pragma unroll
      for (int n = 0; n < 4; ++n)
        bf[n] = *(const half8*)((const char*)Bs + ((wn * 4 + n) * 2 + ks) * 1024 + lane * 16);
      #pragma unroll
      for (int m = 0; m < 4; ++m)
        #pragma unroll
        for (int n = 0; n < 4; ++n)
          acc[m][n] = __builtin_amdgcn_mfma_f32_16x16x32_f16(af[m], bf[n], acc[m][n], 0, 0, 0);
    }
  }

  // ---- epilogue: v[n]*tanh(q+c), reduce this block's 128 columns ----
  float qv[4], vv[4];
  #pragma unroll
  for (int n = 0; n < 4; ++n) {
    const int col = wn * 64 + n * 16 + cL;
    qv[n] = q_l[col];
    vv[n] = v_l[col];
  }
  // C/D layout: col = lane&15, row = quad*4 + reg
  #pragma unroll
  for (int m = 0; m < 4; ++m) {
    #pragma unroll
    for (int r = 0; r < 4; ++r) {
      float s = 0.f;
      #pragma unroll
      for (int n = 0; n < 4; ++n)
        s += vv[n] * fast_tanh(qv[n] + acc[m][n][r]);
      s += __shfl_xor(s, 1);
      s += __shfl_xor(s, 2);
      s += __shfl_xor(s, 4);
      s += __shfl_xor(s, 8);
      if (cL == 0)
        atomicAdd(&rowsum[wm * 64 + m * 16 + quad * 4 + r], s);
    }
  }
  __syncthreads();
  if (tid < TILE)
    partial[(size_t)bn * M_SZ + R0 + tid] = rowsum[tid];

  // ---- last block of this batch performs the masked softmax ----
  __threadfence();               // release partial writes (device scope)
  __syncthreads();
  if (tid == 0)
    last_s = (atomicAdd(&cnt[bidx], 1u) == 127u) ? 1u : 0u;
  __syncthreads();
  if (!last_s) return;
  __threadfence();               // acquire other blocks' partial writes

  const int len = lengths[bidx];
  float lg[8];
  #pragma unroll
  for (int i = 0; i < 8; ++i) {
    const int s = tid + i * 256;
    const size_t row = (size_t)bidx * S_SZ + s;
    float l = 0.f;
    #pragma unroll
    for (int nt = 0; nt < 8; ++nt) l += partial[(size_t)nt * M_SZ + row];
    lg[i] = (s < len) ? l : -INFINITY;
  }

  float mx = lg[0];
  #pragma unroll
  for (int i = 1; i < 8; ++i) mx = fmaxf(mx, lg[i]);
  #pragma unroll
  for (int off = 32; off; off >>= 1) mx = fmaxf(mx, __shfl_xor(mx, off));
  if (lane == 0) red[w] = mx;
  __syncthreads();
  mx = fmaxf(fmaxf(red[0], red[1]), fmaxf(red[2], red[3]));

  float pe[8];
  float sum = 0.f;
  #pragma unroll
  for (int i = 0; i < 8; ++i) {
    float e = (lg[i] == -INFINITY) ? 0.f : __expf(lg[i] - mx);
    pe[i] = e;
    sum += e;
  }
  #pragma unroll
  for (int off = 32; off; off >>= 1) sum += __shfl_xor(sum, off);
  if (lane == 0) red[4 + w] = sum;
  __syncthreads();
  sum = red[4] + red[5] + red[6] + red[7];
  const float inv = 1.0f / sum;

  #pragma unroll
  for (int i = 0; i < 8; ++i) {
    const int s = tid + i * 256;
    out[(size_t)bidx * S_SZ + s] = pe[i] * inv;
  }
}

extern "C" void kernel_launch(void* const* d_in, const int* in_sizes, int n_in,
                              void* d_out, int out_size, void* d_ws, size_t ws_size,
                              hipStream_t stream) {
  const float* hidden  = (const float*)d_in[0];  // (32, 1024)
  const float* enc     = (const float*)d_in[1];  // (32, 2048, 1024)
  const int*   lengths = (const int*)d_in[2];    // (32,)
  const float* Wq      = (const float*)d_in[3];  // (1024, 1024)
  const float* Wk      = (const float*)d_in[4];  // (1024, 1024)
  const float* v       = (const float*)d_in[5];  // (1024,)
  float* out = (float*)d_out;                    // (32, 2048) fp32

  // ws: A16 128 MB | B16 2 MB | q 128 KB | partial 2 MB | cnt 128 B
  char* ws = (char*)d_ws;
  _Float16* A16     = (_Float16*)ws;
  _Float16* B16     = (_Float16*)(ws + 134217728);
  float*    q       = (float*)(ws + 134217728 + 2097152);
  float*    partial = (float*)(ws + 134217728 + 2097152 + 131072);
  unsigned* cnt     = (unsigned*)(ws + 134217728 + 2097152 + 131072 + 2097152);

  prep_kernel<<<16512, 256, 0, stream>>>(enc, (h4*)A16, Wk, (h4*)B16,
                                         hidden, Wq, q, cnt);
  fused_keys_kernel<<<(M_SZ / TILE) * (H_SZ / TILE), 256, 0, stream>>>(
      A16, B16, q, v, lengths, partial, cnt, out);
}

// Round 4
// 866.218 us; speedup vs baseline: 1.0824x; 1.0824x over previous
//
#include <hip/hip_runtime.h>
#include <hip/hip_fp16.h>
#include <stdint.h>

#define B_SZ 32
#define S_SZ 2048
#define H_SZ 1024
#define M_SZ (B_SZ * S_SZ)

typedef _Float16 half8 __attribute__((ext_vector_type(8)));
typedef float floatx4 __attribute__((ext_vector_type(4)));

struct h4 { _Float16 x, y, z, w; };

// ---------------- enc fp32 -> fp16 ----------------
__global__ __launch_bounds__(256) void convert_enc(
    const float* __restrict__ in, h4* __restrict__ out) {
  int i = blockIdx.x * 256 + threadIdx.x;
  const float4* in4 = (const float4*)in;
  #pragma unroll
  for (int r = 0; r < 8; ++r) {
    float4 f = in4[i];
    h4 o;
    o.x = (_Float16)f.x; o.y = (_Float16)f.y;
    o.z = (_Float16)f.z; o.w = (_Float16)f.w;
    out[i] = o;
    i += 8192 * 256;
  }
}

// ---------------- Wk fp32 -> fp16 + zero the softmax counters ----------------
__global__ __launch_bounds__(256) void convert_wk(
    const float* __restrict__ in, h4* __restrict__ out, unsigned* __restrict__ cnt) {
  if (blockIdx.x == 0 && threadIdx.x < B_SZ) cnt[threadIdx.x] = 0u;
  int i = blockIdx.x * 256 + threadIdx.x;
  const float4* in4 = (const float4*)in;
  #pragma unroll
  for (int r = 0; r < 2; ++r) {
    float4 f = in4[i];
    h4 o;
    o.x = (_Float16)f.x; o.y = (_Float16)f.y;
    o.z = (_Float16)f.z; o.w = (_Float16)f.w;
    out[i] = o;
    i += 512 * 256;
  }
}

// ---------------- query = hidden @ Wq^T, one wave per output ----------------
__global__ __launch_bounds__(256) void query_kernel(
    const float* __restrict__ hidden, const float* __restrict__ Wq,
    float* __restrict__ q) {
  const int W = blockIdx.x * 4 + (threadIdx.x >> 6);   // 32768 waves
  const int lane = threadIdx.x & 63;
  const int b = W >> 10;
  const int n = W & 1023;
  const float4* hp = (const float4*)(hidden + (size_t)b * H_SZ);
  const float4* wp = (const float4*)(Wq + (size_t)n * H_SZ);
  float acc = 0.f;
  #pragma unroll
  for (int i = 0; i < 4; ++i) {
    float4 h = hp[lane + 64 * i];
    float4 w = wp[lane + 64 * i];
    acc = fmaf(h.x, w.x, acc);
    acc = fmaf(h.y, w.y, acc);
    acc = fmaf(h.z, w.z, acc);
    acc = fmaf(h.w, w.w, acc);
  }
  #pragma unroll
  for (int off = 32; off; off >>= 1) acc += __shfl_xor(acc, off);
  if (lane == 0) q[(size_t)b * H_SZ + n] = acc;
}

// ---------------- async global->LDS, 16B/lane ----------------
__device__ __forceinline__ void gl_lds16(const void* g, void* l) {
  __builtin_amdgcn_global_load_lds(
      (const __attribute__((address_space(1))) void*)g,
      (__attribute__((address_space(3))) void*)l,
      16, 0, 0);
}

__device__ __forceinline__ float fast_tanh(float x) {
  float ax = fabsf(x);
  float e = __expf(ax * -2.0f);
  float t = (1.0f - e) / (1.0f + e);
  return copysignf(t, x);
}

// ================= fused keys-GEMM + tanh + v-dot + last-block softmax =================
// Exact R1 structure (BK=32, natural per-row staging: 4 lanes cover one 64B row
// segment) + XOR chunk swizzle: lane stages chunk (lane&3)^((lane>>3)&3) of its
// row (same 64B segment per 4-lane group -> coalescing preserved), fragment read
// uses chunk quad^((cL>>1)&3) -> 2-way bank aliasing (free) instead of 8-way.
#define TILE 128
#define BK 32

__global__ __launch_bounds__(256) void fused_keys_kernel(
    const _Float16* __restrict__ A,    // M_SZ x H_SZ fp16
    const _Float16* __restrict__ Bt,   // H_SZ x H_SZ fp16
    const float* __restrict__ q,       // B_SZ x H_SZ
    const float* __restrict__ v,       // H_SZ
    const int* __restrict__ lengths,   // B_SZ
    float* __restrict__ partial,       // 8 x M_SZ
    unsigned* __restrict__ cnt,        // B_SZ (zeroed by convert_wk)
    float* __restrict__ out)           // B_SZ x S_SZ
{
  __shared__ _Float16 As[TILE * BK];   // 8 KB
  __shared__ _Float16 Bs[TILE * BK];   // 8 KB
  __shared__ float rowsum[TILE];
  __shared__ float q_l[TILE];
  __shared__ float v_l[TILE];
  __shared__ float red[8];
  __shared__ unsigned last_s;

  const int tid  = threadIdx.x;
  const int w    = tid >> 6;
  const int lane = tid & 63;

  // XCD swizzle (verified: FETCH 530->85 MB): the 8 blocks sharing an A M-tile
  // are congruent mod 8 -> same XCD L2, dispatched within 64 slots -> co-resident.
  const int bm = ((blockIdx.x >> 6) << 3) | (blockIdx.x & 7);
  const int bn = (blockIdx.x >> 3) & 7;
  const int R0 = bm * TILE;
  const int C0 = bn * TILE;
  const int bidx = R0 >> 11;

  if (tid < TILE) {
    q_l[tid] = q[(size_t)bidx * H_SZ + C0 + tid];
    v_l[tid] = v[C0 + tid];
    rowsum[tid] = 0.f;
  }

  const int wm = w >> 1, wn = w & 1;
  const int cL = lane & 15, quad = lane >> 4;

  floatx4 acc[4][4];
  #pragma unroll
  for (int m = 0; m < 4; ++m)
    #pragma unroll
    for (int n = 0; n < 4; ++n)
      acc[m][n] = (floatx4){0.f, 0.f, 0.f, 0.f};

  const int srow = lane >> 2;                       // 0..15 within a 16-row issue
  const int sw   = (lane & 3) ^ ((lane >> 3) & 3);  // XOR-swizzled chunk index
  const int cq   = quad ^ ((cL >> 1) & 3);          // fragment-read chunk index

  const _Float16* Ablk = A + (size_t)R0 * H_SZ;
  const _Float16* Bblk = Bt + (size_t)C0 * H_SZ;

  for (int kt = 0; kt < H_SZ / BK; ++kt) {
    __syncthreads();
    const int kof = kt * BK;
    #pragma unroll
    for (int r = 0; r < 2; ++r) {
      const int row = w * 16 + r * 64 + srow;
      const int ldsbase = (w * 16 + r * 64) * (BK * 2);   // bytes
      gl_lds16(Ablk + (size_t)row * H_SZ + kof + sw * 8, (char*)As + ldsbase);
      gl_lds16(Bblk + (size_t)row * H_SZ + kof + sw * 8, (char*)Bs + ldsbase);
    }
    __syncthreads();

    half8 af[4], bf[4];
    #pragma unroll
    for (int m = 0; m < 4; ++m)
      af[m] = *(const half8*)(As + (wm * 64 + m * 16 + cL) * BK + cq * 8);
    #pragma unroll
    for (int n = 0; n < 4; ++n)
      bf[n] = *(const half8*)(Bs + (wn * 64 + n * 16 + cL) * BK + cq * 8);
    #pragma unroll
    for (int m = 0; m < 4; ++m)
      #pragma unroll
      for (int n = 0; n < 4; ++n)
        acc[m][n] = __builtin_amdgcn_mfma_f32_16x16x32_f16(af[m], bf[n], acc[m][n], 0, 0, 0);
  }

  // ---- epilogue: v[n]*tanh(q+c), reduce this block's 128 columns ----
  float qv[4], vv[4];
  #pragma unroll
  for (int n = 0; n < 4; ++n) {
    const int col = wn * 64 + n * 16 + cL;
    qv[n] = q_l[col];
    vv[n] = v_l[col];
  }
  // C/D layout: col = lane&15, row = quad*4 + reg
  #pragma unroll
  for (int m = 0; m < 4; ++m) {
    #pragma unroll
    for (int r = 0; r < 4; ++r) {
      float s = 0.f;
      #pragma unroll
      for (int n = 0; n < 4; ++n)
        s += vv[n] * fast_tanh(qv[n] + acc[m][n][r]);
      s += __shfl_xor(s, 1);
      s += __shfl_xor(s, 2);
      s += __shfl_xor(s, 4);
      s += __shfl_xor(s, 8);
      if (cL == 0)
        atomicAdd(&rowsum[wm * 64 + m * 16 + quad * 4 + r], s);
    }
  }
  __syncthreads();
  if (tid < TILE)
    partial[(size_t)bn * M_SZ + R0 + tid] = rowsum[tid];

  // ---- last block of this batch performs the masked softmax (R3-verified) ----
  __threadfence();
  __syncthreads();
  if (tid == 0)
    last_s = (atomicAdd(&cnt[bidx], 1u) == 127u) ? 1u : 0u;
  __syncthreads();
  if (!last_s) return;
  __threadfence();

  const int len = lengths[bidx];
  float lg[8];
  #pragma unroll
  for (int i = 0; i < 8; ++i) {
    const int s = tid + i * 256;
    const size_t row = (size_t)bidx * S_SZ + s;
    float l = 0.f;
    #pragma unroll
    for (int nt = 0; nt < 8; ++nt) l += partial[(size_t)nt * M_SZ + row];
    lg[i] = (s < len) ? l : -INFINITY;
  }

  float mx = lg[0];
  #pragma unroll
  for (int i = 1; i < 8; ++i) mx = fmaxf(mx, lg[i]);
  #pragma unroll
  for (int off = 32; off; off >>= 1) mx = fmaxf(mx, __shfl_xor(mx, off));
  if (lane == 0) red[w] = mx;
  __syncthreads();
  mx = fmaxf(fmaxf(red[0], red[1]), fmaxf(red[2], red[3]));

  float pe[8];
  float sum = 0.f;
  #pragma unroll
  for (int i = 0; i < 8; ++i) {
    float e = (lg[i] == -INFINITY) ? 0.f : __expf(lg[i] - mx);
    pe[i] = e;
    sum += e;
  }
  #pragma unroll
  for (int off = 32; off; off >>= 1) sum += __shfl_xor(sum, off);
  if (lane == 0) red[4 + w] = sum;
  __syncthreads();
  sum = red[4] + red[5] + red[6] + red[7];
  const float inv = 1.0f / sum;

  #pragma unroll
  for (int i = 0; i < 8; ++i) {
    const int s = tid + i * 256;
    out[(size_t)bidx * S_SZ + s] = pe[i] * inv;
  }
}

extern "C" void kernel_launch(void* const* d_in, const int* in_sizes, int n_in,
                              void* d_out, int out_size, void* d_ws, size_t ws_size,
                              hipStream_t stream) {
  const float* hidden  = (const float*)d_in[0];  // (32, 1024)
  const float* enc     = (const float*)d_in[1];  // (32, 2048, 1024)
  const int*   lengths = (const int*)d_in[2];    // (32,)
  const float* Wq      = (const float*)d_in[3];  // (1024, 1024)
  const float* Wk      = (const float*)d_in[4];  // (1024, 1024)
  const float* v       = (const float*)d_in[5];  // (1024,)
  float* out = (float*)d_out;                    // (32, 2048) fp32

  // ws: A16 128 MB | B16 2 MB | q 128 KB | partial 2 MB | cnt 128 B
  char* ws = (char*)d_ws;
  _Float16* A16     = (_Float16*)ws;
  _Float16* B16     = (_Float16*)(ws + 134217728);
  float*    q       = (float*)(ws + 134217728 + 2097152);
  float*    partial = (float*)(ws + 134217728 + 2097152 + 131072);
  unsigned* cnt     = (unsigned*)(ws + 134217728 + 2097152 + 131072 + 2097152);

  convert_enc<<<8192, 256, 0, stream>>>(enc, (h4*)A16);
  convert_wk<<<512, 256, 0, stream>>>(Wk, (h4*)B16, cnt);
  query_kernel<<<8192, 256, 0, stream>>>(hidden, Wq, q);
  fused_keys_kernel<<<(M_SZ / TILE) * (H_SZ / TILE), 256, 0, stream>>>(
      A16, B16, q, v, lengths, partial, cnt, out);
}